// Round 11
// baseline (244.604 us; speedup 1.0000x reference)
//
#include <hip/hip_runtime.h>

// GCN 2-layer, N=100k, E=3.2M, IN=2, HID=64, OUT=1 (all float32).
// R11: single fused kernel (256 blocks x 1024 thr, ~35KB LDS -> all blocks
// resident) with hand-rolled agent-scope barriers between phases:
//   sort(2 staged rounds) | hist->dinv,y | s1->MLP->t | s2->out.
// Barrier: thread0 atomicAdd(release) + acquire-load spin + s_sleep backoff
// (R7 showed cg::grid.sync costs ~70us/sync; this should be ~3-5us).
// 256 buckets x 392 nodes; packed edge = (lcol<<17)|row.

#define NBUCK 256
#define BSH   392        // nodes per bucket (256*392 = 100352 >= n)
#define RBITS 17
#define RMASK ((1 << RBITS) - 1)
#define CAP   13500      // packed region per bucket (mean 12.5k, +9 sigma)
#define SCP   32         // staging per (block,bucket,round): mean 24.4
#define GRID  256
#define TPB   1024

struct SortLDS { int fill[NBUCK]; int gb[NBUCK]; int stage[NBUCK * SCP]; };
union U {
    SortLDS sort;        // 34 KB
    int     hist[BSH];
    float2  acc2[BSH];
    float   acc1[BSH];
};

__global__ void k_init0(int* __restrict__ gcur, int* __restrict__ bar) {
    if (threadIdx.x < NBUCK) gcur[threadIdx.x] = threadIdx.x * CAP;
    if (threadIdx.x < 8) bar[threadIdx.x] = 0;
}

__device__ __forceinline__ void gbar(int* __restrict__ bar, int phase) {
    __syncthreads();
    if (threadIdx.x == 0) {
        __threadfence();   // device-scope release of this block's writes
        __hip_atomic_fetch_add(&bar[phase], 1, __ATOMIC_ACQ_REL,
                               __HIP_MEMORY_SCOPE_AGENT);
        while (__hip_atomic_load(&bar[phase], __ATOMIC_ACQUIRE,
                                 __HIP_MEMORY_SCOPE_AGENT) < GRID)
            __builtin_amdgcn_s_sleep(2);
    }
    __syncthreads();
}

__device__ __forceinline__ void sort_one(int c, int r, int* fill, int* stage,
                                         int* __restrict__ gcur,
                                         int* __restrict__ packed) {
    int b = (int)((unsigned)c / (unsigned)BSH);   // magic-mul div by 392
    int l = c - b * BSH;
    int w = (l << RBITS) | r;
    int p = atomicAdd(&fill[b], 1);
    if (p < SCP) stage[b * SCP + p] = w;
    else packed[atomicAdd(&gcur[b], 1)] = w;      // rare spill, still correct
}

__global__ void __launch_bounds__(TPB)
k_all(const float2* __restrict__ x, const int* __restrict__ row,
      const int* __restrict__ col,
      const float* __restrict__ W1, const float* __restrict__ B1,
      const float* __restrict__ W2, const float* __restrict__ B2,
      int* __restrict__ gcur, int* __restrict__ bar, int* __restrict__ packed,
      float* __restrict__ dinv, float2* __restrict__ y, float* __restrict__ t,
      float* __restrict__ out, int n, int E) {
    __shared__ U u;
    __shared__ float w1a[64], w1b[64], bb1[64], w2s[64];
    const int tid = threadIdx.x, bid = blockIdx.x;
    if (tid < 64) {
        w1a[tid] = W1[tid];
        w1b[tid] = W1[64 + tid];
        bb1[tid] = B1[tid];
        w2s[tid] = W2[tid];
    }

    // ---- phase 0: staged counting sort by dest bucket (2 rounds) ----
    {
        const int q = E >> 2;
        const int4* c4 = (const int4*)col;
        const int4* r4 = (const int4*)row;
        for (int round = 0; round < 2; ++round) {
            if (tid < NBUCK) u.sort.fill[tid] = 0;
            __syncthreads();
            const int seg = 2 * bid + round;
            const int q0 = (int)((long long)q * seg / (2 * GRID));
            const int q1 = (int)((long long)q * (seg + 1) / (2 * GRID));
            for (int i = q0 + tid; i < q1; i += TPB) {
                int4 c = c4[i], r = r4[i];
                sort_one(c.x, r.x, u.sort.fill, u.sort.stage, gcur, packed);
                sort_one(c.y, r.y, u.sort.fill, u.sort.stage, gcur, packed);
                sort_one(c.z, r.z, u.sort.fill, u.sort.stage, gcur, packed);
                sort_one(c.w, r.w, u.sort.fill, u.sort.stage, gcur, packed);
            }
            if (round == 1 && bid == GRID - 1)   // tail if E % 4 != 0
                for (int e = (q << 2) + tid; e < E; e += TPB)
                    sort_one(col[e], row[e], u.sort.fill, u.sort.stage, gcur, packed);
            __syncthreads();
            if (tid < NBUCK)
                u.sort.gb[tid] = atomicAdd(&gcur[tid], min(u.sort.fill[tid], SCP));
            __syncthreads();
            const int wid = tid >> 6, lane = tid & 63;
            for (int b = wid; b < NBUCK; b += (TPB >> 6)) {  // coalesced copy-out
                int cnt = min(u.sort.fill[b], SCP);          // cnt <= 32 <= wave
                if (lane < cnt) packed[u.sort.gb[b] + lane] = u.sort.stage[b * SCP + lane];
            }
            __syncthreads();
        }
    }
    gbar(bar, 0);

    const int base = bid * CAP;
    const int len = gcur[bid] - base;        // final after barrier
    const int4* p4 = (const int4*)(packed + base);
    const int q = len >> 2;

    // ---- phase 1: in-degree hist -> dinv; y = dinv*x ----
    {
        if (tid < BSH) u.hist[tid] = 0;
        __syncthreads();
        for (int i = tid; i < q; i += TPB) {
            int4 w = p4[i];
            atomicAdd(&u.hist[w.x >> RBITS], 1);
            atomicAdd(&u.hist[w.y >> RBITS], 1);
            atomicAdd(&u.hist[w.z >> RBITS], 1);
            atomicAdd(&u.hist[w.w >> RBITS], 1);
        }
        for (int e = (q << 2) + tid; e < len; e += TPB)
            atomicAdd(&u.hist[packed[base + e] >> RBITS], 1);
        __syncthreads();
        if (tid < BSH) {
            int i = bid * BSH + tid;
            if (i < n) {
                float d = rsqrtf((float)(1 + u.hist[tid]));   // +1 self-loop
                dinv[i] = d;
                float2 xv = x[i];
                y[i] = make_float2(d * xv.x, d * xv.y);
            }
        }
    }
    gbar(bar, 1);

    // ---- phase 2: s1 scatter + MLP epilogue -> t ----
    {
        if (tid < BSH) u.acc2[tid] = make_float2(0.f, 0.f);
        __syncthreads();
        for (int i = tid; i < q; i += TPB) {
            int4 w = p4[i];
            float2 v; float* sp;
            v = y[w.x & RMASK]; sp = (float*)&u.acc2[w.x >> RBITS];
            atomicAdd(sp, v.x); atomicAdd(sp + 1, v.y);
            v = y[w.y & RMASK]; sp = (float*)&u.acc2[w.y >> RBITS];
            atomicAdd(sp, v.x); atomicAdd(sp + 1, v.y);
            v = y[w.z & RMASK]; sp = (float*)&u.acc2[w.z >> RBITS];
            atomicAdd(sp, v.x); atomicAdd(sp + 1, v.y);
            v = y[w.w & RMASK]; sp = (float*)&u.acc2[w.w >> RBITS];
            atomicAdd(sp, v.x); atomicAdd(sp + 1, v.y);
        }
        for (int e = (q << 2) + tid; e < len; e += TPB) {
            int w = packed[base + e];
            float2 v = y[w & RMASK];
            float* sp = (float*)&u.acc2[w >> RBITS];
            atomicAdd(sp, v.x); atomicAdd(sp + 1, v.y);
        }
        __syncthreads();
        if (tid < BSH) {
            int i = bid * BSH + tid;
            if (i < n) {
                float d = dinv[i];
                float2 yv = y[i];
                float a0 = d * (u.acc2[tid].x + yv.x);
                float a1 = d * (u.acc2[tid].y + yv.y);
                float acc = 0.f;
#pragma unroll
                for (int h = 0; h < 64; ++h) {
                    float v = fmaf(a0, w1a[h], fmaf(a1, w1b[h], bb1[h]));
                    acc = fmaf(fmaxf(v, 0.f), w2s[h], acc);
                }
                t[i] = d * acc;
            }
        }
    }
    gbar(bar, 2);

    // ---- phase 3: s2 scatter + output epilogue ----
    {
        if (tid < BSH) u.acc1[tid] = 0.f;
        __syncthreads();
        for (int i = tid; i < q; i += TPB) {
            int4 w = p4[i];
            atomicAdd(&u.acc1[w.x >> RBITS], t[w.x & RMASK]);
            atomicAdd(&u.acc1[w.y >> RBITS], t[w.y & RMASK]);
            atomicAdd(&u.acc1[w.z >> RBITS], t[w.z & RMASK]);
            atomicAdd(&u.acc1[w.w >> RBITS], t[w.w & RMASK]);
        }
        for (int e = (q << 2) + tid; e < len; e += TPB) {
            int w = packed[base + e];
            atomicAdd(&u.acc1[w >> RBITS], t[w & RMASK]);
        }
        __syncthreads();
        if (tid < BSH) {
            int i = bid * BSH + tid;
            if (i < n) out[i] = fmaf(dinv[i], u.acc1[tid] + t[i], B2[0]);
        }
    }
}

extern "C" void kernel_launch(void* const* d_in, const int* in_sizes, int n_in,
                              void* d_out, int out_size, void* d_ws, size_t ws_size,
                              hipStream_t stream) {
    const float* x  = (const float*)d_in[0];
    const int*   ei = (const int*)d_in[1];
    const float* W1 = (const float*)d_in[2];
    const float* B1 = (const float*)d_in[3];
    const float* W2 = (const float*)d_in[4];
    const float* B2 = (const float*)d_in[5];
    float* out = (float*)d_out;

    const int n = in_sizes[0] / 2;      // 100,000
    const int E = in_sizes[1] / 2;      // 3,200,000
    const int* row = ei;
    const int* col = ei + E;

    // ws: dinv[n] | y[n](f2) | t[n] | gcur[256] | bar[8] | packed[256*CAP]
    char* ws = (char*)d_ws;
    size_t off = 0;
    float*  dinv = (float*)(ws + off);  off += (size_t)n * 4;
    float2* y    = (float2*)(ws + off); off += (size_t)n * 8;
    float*  t    = (float*)(ws + off);  off += (size_t)n * 4;
    off = (off + 255) & ~(size_t)255;
    int* gcur    = (int*)(ws + off);    off += (size_t)NBUCK * 4;
    int* bar     = (int*)(ws + off);    off += 256;
    off = (off + 255) & ~(size_t)255;
    int* packed  = (int*)(ws + off);

    k_init0<<<1, NBUCK, 0, stream>>>(gcur, bar);
    k_all<<<GRID, TPB, 0, stream>>>((const float2*)x, row, col, W1, B1, W2, B2,
                                    gcur, bar, packed, dinv, y, t, out, n, E);
}

// Round 12
// 158.123 us; speedup vs baseline: 1.5469x; 1.5469x over previous
//
#include <hip/hip_runtime.h>

// GCN 2-layer, N=100k, E=3.2M, IN=2, HID=64, OUT=1 (all float32).
// R12 = R10 structure (best: 166.6us) with 512 buckets x 196 nodes so every
// scan kernel runs 512 blocks x 1024 thr = 2 blocks/CU = 32 waves/CU (R10's
// scans were 1 block/CU = 16 waves). Pipeline: staged counting sort by dest
// bucket -> hist+dinv,y -> s1+MLP->t -> s2+out. 5 launches, zero global
// atomics on hot paths (rare sort spills only). R11's fused/barrier variant
// regressed (agent-scope fences cold the L2s; ~25us/boundary) - abandoned.

#define NBUCK 512
#define BSH   196        // nodes per bucket (512*196 = 100352 >= n)
#define RBITS 17         // row bits (n < 131072)
#define RMASK ((1 << RBITS) - 1)
#define CAP   6750       // packed region per bucket (mean 6250, +6.3 sigma)
#define SORTB 512
#define SCAPS 24         // staging per (block,bucket): mean 12.2, +3.4 sigma
#define TPS   1024
#define TPB   1024

__global__ void k_init0(int* __restrict__ gcur) {
    int i = blockIdx.x * 256 + threadIdx.x;
    if (i < NBUCK) gcur[i] = i * CAP;
}

__device__ __forceinline__ void sort_one(int c, int r, int* fill, int* stage,
                                         int* __restrict__ gcur,
                                         int* __restrict__ packed) {
    int b = (int)((unsigned)c / (unsigned)BSH);   // magic-mul div by 196
    int l = c - b * BSH;
    int w = (l << RBITS) | r;
    int p = atomicAdd(&fill[b], 1);
    if (p < SCAPS) stage[b * SCAPS + p] = w;
    else packed[atomicAdd(&gcur[b], 1)] = w;      // rare spill, still correct
}

// staged counting sort by dest bucket: packed[b-region] gets ((lcol<<17)|row)
__global__ void __launch_bounds__(TPS)
k_sort(const int* __restrict__ row, const int* __restrict__ col,
       int* __restrict__ gcur, int* __restrict__ packed, int E) {
    __shared__ int fill[NBUCK];
    __shared__ int gb[NBUCK];
    __shared__ int stage[NBUCK * SCAPS];   // 49 KB
    const int tid = threadIdx.x, bid = blockIdx.x;
    for (int i = tid; i < NBUCK; i += TPS) fill[i] = 0;
    __syncthreads();
    const int q = E >> 2;
    const int q0 = (int)((long long)bid * q / SORTB);
    const int q1 = (int)((long long)(bid + 1) * q / SORTB);
    const int4* c4 = (const int4*)col;
    const int4* r4 = (const int4*)row;
    for (int i = q0 + tid; i < q1; i += TPS) {
        int4 c = c4[i], r = r4[i];
        sort_one(c.x, r.x, fill, stage, gcur, packed);
        sort_one(c.y, r.y, fill, stage, gcur, packed);
        sort_one(c.z, r.z, fill, stage, gcur, packed);
        sort_one(c.w, r.w, fill, stage, gcur, packed);
    }
    if (bid == SORTB - 1)   // tail if E % 4 != 0
        for (int e = (q << 2) + tid; e < E; e += TPS)
            sort_one(col[e], row[e], fill, stage, gcur, packed);
    __syncthreads();
    for (int b = tid; b < NBUCK; b += TPS)
        gb[b] = atomicAdd(&gcur[b], min(fill[b], SCAPS));
    __syncthreads();
    const int wid = tid >> 6, lane = tid & 63;
    for (int b = wid; b < NBUCK; b += (TPS >> 6)) {  // per-wave coalesced copy-out
        int cnt = min(fill[b], SCAPS);               // cnt <= 24 < wave
        if (lane < cnt) packed[gb[b] + lane] = stage[b * SCAPS + lane];
    }
}

// hist + epilogue: deg -> dinv; y = dinv*x   (one block = one whole bucket)
__global__ void __launch_bounds__(TPB)
k_h1(const int* __restrict__ gcur, const int* __restrict__ packed,
     const float2* __restrict__ x, float* __restrict__ dinv,
     float2* __restrict__ y, int n) {
    __shared__ int s[BSH];
    const int b = blockIdx.x;
    if (threadIdx.x < BSH) s[threadIdx.x] = 0;
    __syncthreads();
    const int base = b * CAP;
    const int len = gcur[b] - base;
    const int q = len >> 2;
    const int4* p4 = (const int4*)(packed + base);
    for (int i = threadIdx.x; i < q; i += TPB) {
        int4 w = p4[i];
        atomicAdd(&s[w.x >> RBITS], 1);
        atomicAdd(&s[w.y >> RBITS], 1);
        atomicAdd(&s[w.z >> RBITS], 1);
        atomicAdd(&s[w.w >> RBITS], 1);
    }
    for (int e = (q << 2) + threadIdx.x; e < len; e += TPB)
        atomicAdd(&s[packed[base + e] >> RBITS], 1);
    __syncthreads();
    if (threadIdx.x < BSH) {
        int i = b * BSH + threadIdx.x;
        if (i < n) {
            float d = rsqrtf((float)(1 + s[threadIdx.x]));   // +1 self-loop
            dinv[i] = d;
            float2 xv = x[i];
            y[i] = make_float2(d * xv.x, d * xv.y);
        }
    }
}

// s1 + MLP epilogue: agg = sum y[row]; t = dinv*(relu((dinv*(agg+y))@W1+b1)@W2)
__global__ void __launch_bounds__(TPB)
k_sc1(const int* __restrict__ gcur, const int* __restrict__ packed,
      const float2* __restrict__ y, const float* __restrict__ dinv,
      const float* __restrict__ W1, const float* __restrict__ B1,
      const float* __restrict__ W2, float* __restrict__ t, int n) {
    __shared__ float2 s[BSH];
    __shared__ float w1a[64], w1b[64], bb1[64], w2[64];
    if (threadIdx.x >= 256 && threadIdx.x < 320) {
        int h = threadIdx.x - 256;
        w1a[h] = W1[h];
        w1b[h] = W1[64 + h];
        bb1[h] = B1[h];
        w2[h]  = W2[h];
    }
    if (threadIdx.x < BSH) s[threadIdx.x] = make_float2(0.f, 0.f);
    __syncthreads();
    const int b = blockIdx.x;
    const int base = b * CAP;
    const int len = gcur[b] - base;
    const int q = len >> 2;
    const int4* p4 = (const int4*)(packed + base);
    for (int i = threadIdx.x; i < q; i += TPB) {
        int4 w = p4[i];
        float2 v; float* sp;
        v = y[w.x & RMASK]; sp = (float*)&s[w.x >> RBITS];
        atomicAdd(sp, v.x); atomicAdd(sp + 1, v.y);
        v = y[w.y & RMASK]; sp = (float*)&s[w.y >> RBITS];
        atomicAdd(sp, v.x); atomicAdd(sp + 1, v.y);
        v = y[w.z & RMASK]; sp = (float*)&s[w.z >> RBITS];
        atomicAdd(sp, v.x); atomicAdd(sp + 1, v.y);
        v = y[w.w & RMASK]; sp = (float*)&s[w.w >> RBITS];
        atomicAdd(sp, v.x); atomicAdd(sp + 1, v.y);
    }
    for (int e = (q << 2) + threadIdx.x; e < len; e += TPB) {
        int w = packed[base + e];
        float2 v = y[w & RMASK];
        float* sp = (float*)&s[w >> RBITS];
        atomicAdd(sp, v.x); atomicAdd(sp + 1, v.y);
    }
    __syncthreads();
    if (threadIdx.x < BSH) {
        int i = b * BSH + threadIdx.x;
        if (i < n) {
            float d = dinv[i];
            float2 yv = y[i];
            float a0 = d * (s[threadIdx.x].x + yv.x);
            float a1 = d * (s[threadIdx.x].y + yv.y);
            float acc = 0.f;
#pragma unroll
            for (int h = 0; h < 64; ++h) {
                float v = fmaf(a0, w1a[h], fmaf(a1, w1b[h], bb1[h]));
                acc = fmaf(fmaxf(v, 0.f), w2[h], acc);
            }
            t[i] = d * acc;
        }
    }
}

// s2 + output epilogue: o = sum t[row]; out = dinv*(o + t_self) + b2
__global__ void __launch_bounds__(TPB)
k_sc2(const int* __restrict__ gcur, const int* __restrict__ packed,
      const float* __restrict__ t, const float* __restrict__ dinv,
      const float* __restrict__ B2, float* __restrict__ out, int n) {
    __shared__ float s[BSH];
    const int b = blockIdx.x;
    if (threadIdx.x < BSH) s[threadIdx.x] = 0.f;
    __syncthreads();
    const int base = b * CAP;
    const int len = gcur[b] - base;
    const int q = len >> 2;
    const int4* p4 = (const int4*)(packed + base);
    for (int i = threadIdx.x; i < q; i += TPB) {
        int4 w = p4[i];
        atomicAdd(&s[w.x >> RBITS], t[w.x & RMASK]);
        atomicAdd(&s[w.y >> RBITS], t[w.y & RMASK]);
        atomicAdd(&s[w.z >> RBITS], t[w.z & RMASK]);
        atomicAdd(&s[w.w >> RBITS], t[w.w & RMASK]);
    }
    for (int e = (q << 2) + threadIdx.x; e < len; e += TPB) {
        int w = packed[base + e];
        atomicAdd(&s[w >> RBITS], t[w & RMASK]);
    }
    __syncthreads();
    if (threadIdx.x < BSH) {
        int i = b * BSH + threadIdx.x;
        if (i < n) out[i] = fmaf(dinv[i], s[threadIdx.x] + t[i], B2[0]);
    }
}

extern "C" void kernel_launch(void* const* d_in, const int* in_sizes, int n_in,
                              void* d_out, int out_size, void* d_ws, size_t ws_size,
                              hipStream_t stream) {
    const float* x  = (const float*)d_in[0];
    const int*   ei = (const int*)d_in[1];
    const float* W1 = (const float*)d_in[2];
    const float* B1 = (const float*)d_in[3];
    const float* W2 = (const float*)d_in[4];
    const float* B2 = (const float*)d_in[5];
    float* out = (float*)d_out;

    const int n = in_sizes[0] / 2;      // 100,000
    const int E = in_sizes[1] / 2;      // 3,200,000
    const int* row = ei;
    const int* col = ei + E;

    // ws: dinv[n] | y[n](f2) | t[n] | gcur[512] | packed[512*CAP ~13.8MB]
    char* ws = (char*)d_ws;
    size_t off = 0;
    float*  dinv = (float*)(ws + off);  off += (size_t)n * 4;
    float2* y    = (float2*)(ws + off); off += (size_t)n * 8;
    float*  t    = (float*)(ws + off);  off += (size_t)n * 4;
    off = (off + 255) & ~(size_t)255;
    int* gcur    = (int*)(ws + off);    off += (size_t)NBUCK * 4;
    off = (off + 255) & ~(size_t)255;
    int* packed  = (int*)(ws + off);

    k_init0<<<2, 256, 0, stream>>>(gcur);
    k_sort <<<SORTB, TPS, 0, stream>>>(row, col, gcur, packed, E);
    k_h1   <<<NBUCK, TPB, 0, stream>>>(gcur, packed, (const float2*)x, dinv, y, n);
    k_sc1  <<<NBUCK, TPB, 0, stream>>>(gcur, packed, y, dinv, W1, B1, W2, t, n);
    k_sc2  <<<NBUCK, TPB, 0, stream>>>(gcur, packed, t, dinv, B2, out, n);
}